// Round 13
// baseline (659.526 us; speedup 1.0000x reference)
//
#include <hip/hip_runtime.h>

#define HID 128
#define AROWS 173   // sum(ATOM_DIMS) = 173 (offsets end at 171, last dim = 2)

// Global feature-dim permutation: phys position p holds logical column
// c(p) = (p&7)*16 + (p>>3).  Inverse: p(c) = (c&15)*8 + (c>>4).
// Makes the MFMA C-fragment contiguous in phys layout -> gemm needs no LDS.
__device__ __forceinline__ int lcol(int p) { return ((p & 7) << 4) | (p >> 3); }

typedef __attribute__((ext_vector_type(8))) short short8;
typedef __attribute__((ext_vector_type(8))) unsigned short ushort8v;
typedef __attribute__((ext_vector_type(4))) float floatx4;
typedef __attribute__((ext_vector_type(4))) unsigned short ushort4v;

__device__ __forceinline__ unsigned short f2bf(float f) {
    unsigned u = __builtin_bit_cast(unsigned, f);
    u += 0x7FFF + ((u >> 16) & 1);           // RNE
    return (unsigned short)(u >> 16);
}
__device__ __forceinline__ float bf2f(unsigned short s) {
    unsigned u = ((unsigned)s) << 16;
    return __builtin_bit_cast(float, u);
}

// ---------------- diagnostic ----------------
__global__ void diag_kernel(float* __restrict__ out, long n, float val)
{
    long i = (long)blockIdx.x * blockDim.x + threadIdx.x;
    if (i < n) out[i] = val;
}

// ---------------- merged init: fillrd | tables (permuted) | EW gemm ----------
// blocks [0,NB): zero dis+indeg | [NB,NB+64): conv_W cvt | +64..128: lin_W cvt
// | +128..158: comb fp32 | +158: BN/root/cb | +159..246: EW rows (2/block)
__global__ __launch_bounds__(256) void init_kernel(
    float* __restrict__ dis, int* __restrict__ indeg, int NB, int N,
    const float* __restrict__ conv_W, unsigned short* __restrict__ Wb,
    const float* __restrict__ lin_W, unsigned short* __restrict__ linWb,
    const float* __restrict__ bond_emb, float* __restrict__ comb,
    const float* __restrict__ gamma, const float* __restrict__ beta,
    const float* __restrict__ mean, const float* __restrict__ var,
    float* __restrict__ bnsc, float* __restrict__ bnsh,
    const float* __restrict__ root, const float* __restrict__ conv_b,
    float* __restrict__ rootp, float* __restrict__ cbp,
    const float* __restrict__ atom_emb, unsigned short* __restrict__ EWb)
{
    int blk = blockIdx.x;
    int tid = threadIdx.x;
    if (blk < NB) {
        int i = blk * 256 + tid;
        if (i < N) { dis[i] = 0.f; indeg[i] = 0; }
        return;
    }
    blk -= NB;
    if (blk < 64) {
        int i = blk * 256 + tid;
        int row = i >> 7, p = i & 127;
        Wb[i] = f2bf(conv_W[row * HID + lcol(p)]);
    } else if (blk < 128) {
        int i = (blk - 64) * 256 + tid;
        int row = i >> 7, p = i & 127;
        linWb[i] = f2bf(lin_W[row * HID + lcol(p)]);
    } else if (blk < 158) {
        int i = (blk - 128) * 2 + (tid >> 7);     // combo row
        int p = tid & 127;
        int c = lcol(p);
        int a0 = i / 12, a1 = (i % 12) / 2, a2 = i % 2;
        comb[i * HID + p] = bond_emb[a0 * HID + c] + bond_emb[(5 + a1) * HID + c]
                          + bond_emb[(11 + a2) * HID + c];
    } else if (blk == 158) {
        if (tid < HID) {
            int c = lcol(tid);
            float sc = gamma[c] * rsqrtf(var[c] + 1e-5f);
            bnsc[tid] = sc;
            bnsh[tid] = beta[c] - mean[c] * sc;
            rootp[tid] = root[c];
            cbp[tid] = conv_b[c];
        }
    } else {
        // EW = atom_emb @ conv_W^T, 2 rows/block, stored permuted
        int r = (blk - 159) * 2 + (tid >> 7);
        if (r >= AROWS) return;
        int c = tid & 127;                        // logical col
        const float* er = atom_emb + (long)r * HID;
        const float* wr = conv_W + (long)c * HID;
        float acc = 0.f;
#pragma unroll 4
        for (int k = 0; k < HID; k += 4) {
            floatx4 e4 = *reinterpret_cast<const floatx4*>(er + k);
            floatx4 w4 = *reinterpret_cast<const floatx4*>(wr + k);
            acc += e4[0] * w4[0] + e4[1] * w4[1] + e4[2] * w4[2] + e4[3] * w4[3];
        }
        EWb[(long)r * HID + ((c & 15) * 8 + (c >> 4))] = f2bf(acc);
    }
}

// ---------------- merged: out-degree (row, into dis) + in-degree (col) -------
__global__ void hist_kernel(const int* __restrict__ ei, float* __restrict__ dis,
                            int* __restrict__ indeg, int E)
{
    for (int e = blockIdx.x * blockDim.x + threadIdx.x; e < E; e += gridDim.x * blockDim.x) {
        atomicAdd(&dis[ei[e]], 1.f);
        atomicAdd(&indeg[ei[E + e]], 1);
    }
}

// ---------------- CSR scan chain (node order) + fdeg fold --------------------
__global__ __launch_bounds__(256) void bsum_kernel(
    const int* __restrict__ indeg, int* __restrict__ partial,
    float* __restrict__ dis, int N)
{
    __shared__ int s[256];
    int tid = threadIdx.x;
    int i = blockIdx.x * 256 + tid;
    int v = (i < N) ? indeg[i] : 0;
    s[tid] = v;
    if (i < N) dis[i] = rsqrtf(dis[i] + 1.f);     // fdeg folded (hist complete)
    __syncthreads();
    for (int d = 128; d > 0; d >>= 1) {
        if (tid < d) s[tid] += s[tid + d];
        __syncthreads();
    }
    if (tid == 0) partial[blockIdx.x] = s[0];
}

__global__ __launch_bounds__(256) void scan1_kernel(
    const int* __restrict__ partial, int* __restrict__ offs,
    int* __restrict__ ptr, int B, int N)
{
    __shared__ int s[256];
    __shared__ int carry_s;
    int tid = threadIdx.x;
    if (tid == 0) carry_s = 0;
    __syncthreads();
    for (int base = 0; base < B; base += 256) {
        int i = base + tid;
        int v = (i < B) ? partial[i] : 0;
        s[tid] = v;
        __syncthreads();
        for (int d = 1; d < 256; d <<= 1) {
            int t = (tid >= d) ? s[tid - d] : 0;
            __syncthreads();
            s[tid] += t;
            __syncthreads();
        }
        int carry = carry_s;
        if (i < B) offs[i] = carry + s[tid] - v;
        __syncthreads();
        if (tid == 0) carry_s = carry + s[255];
        __syncthreads();
    }
    if (tid == 0) ptr[N] = carry_s;
}

// in-place safe: cursor may alias indeg (read-before-write per element)
__global__ __launch_bounds__(256) void scan2_kernel(
    const int* __restrict__ indeg, const int* __restrict__ offs,
    int* __restrict__ ptr, int* __restrict__ cursor, int N)
{
    __shared__ int s[256];
    int tid = threadIdx.x;
    int i = blockIdx.x * 256 + tid;
    int v = (i < N) ? indeg[i] : 0;
    s[tid] = v;
    __syncthreads();
    for (int d = 1; d < 256; d <<= 1) {
        int t = (tid >= d) ? s[tid - d] : 0;
        __syncthreads();
        s[tid] += t;
        __syncthreads();
    }
    if (i < N) {
        int ex = offs[blockIdx.x] + s[tid] - v;
        ptr[i] = ex;
        cursor[i] = ex;
    }
}

// ---------------- CSR fill {row, ci, f32 nrm, 0} + (folded) gptr -------------
__global__ void fillcsr_kernel(const int* __restrict__ ei, const int* __restrict__ attr,
                               const float* __restrict__ dis, int* __restrict__ cursor,
                               int4* __restrict__ edata, const int* __restrict__ batch,
                               int* __restrict__ gptr, int E, int N, int G)
{
    for (int e = blockIdx.x * blockDim.x + threadIdx.x; e < E; e += gridDim.x * blockDim.x) {
        int r   = ei[e];
        int col = ei[E + e];
        int pos = atomicAdd(&cursor[col], 1);
        int ci  = attr[e * 3] * 12 + attr[e * 3 + 1] * 2 + attr[e * 3 + 2];
        float nrm = dis[r] * dis[col];
        int4 ed;
        ed.x = r;
        ed.y = ci;
        ed.z = __builtin_bit_cast(int, nrm);
        ed.w = 0;
        edata[pos] = ed;
    }
    for (int n = blockIdx.x * blockDim.x + threadIdx.x; n < N; n += gridDim.x * blockDim.x) {
        int b = batch[n];
        int bp = (n == 0) ? -1 : batch[n - 1];
        for (int g = bp + 1; g <= b; ++g) gptr[g] = n;
        if (n == N - 1)
            for (int g = b + 1; g <= G; ++g) gptr[g] = N;
    }
}

// ---------------- encode: z = sum_f EW[idx_f] + b (permuted layout) ----------
__global__ __launch_bounds__(256) void enc_kernel(
    const int* __restrict__ x, const unsigned short* __restrict__ EWb,
    const float* __restrict__ cbp, unsigned short* __restrict__ zb, int N)
{
    long n = (long)blockIdx.x * 16 + (threadIdx.x >> 4);
    if (n >= N) return;
    int c = (threadIdx.x & 15) * 8;
    const int OFF[9] = {0, 119, 123, 135, 147, 157, 163, 169, 171};

    float acc[8];
#pragma unroll
    for (int j = 0; j < 8; ++j) acc[j] = cbp[c + j];

#pragma unroll
    for (int f = 0; f < 9; ++f) {
        int idx = x[n * 9 + f] + OFF[f];              // 16-lane broadcast load
        ushort8v v = *reinterpret_cast<const ushort8v*>(EWb + (long)idx * HID + c);
#pragma unroll
        for (int j = 0; j < 8; ++j) acc[j] += bf2f(v[j]);
    }

    ushort8v o;
#pragma unroll
    for (int j = 0; j < 8; ++j) o[j] = f2bf(acc[j]);
    *reinterpret_cast<ushort8v*>(zb + n * HID + c) = o;
}

// ---------------- agg: one node per 16-lane group (permuted layout) ----------
// fp32 comb + pre-decoded edata (f32 nrm, bare ci) cut ~10 VALU ops/edge
// (8 comb unpacks + nrm unpack + ci mask) — agg was 54% VALU / 45% HBM mixed.
template<bool FIRST>
__global__ __launch_bounds__(256) void agg_kernel(
    const int* __restrict__ ptr, const int4* __restrict__ edata,
    const float* __restrict__ comb, const float* __restrict__ dis,
    const float* __restrict__ root, const float* __restrict__ bnsc,
    const float* __restrict__ bnsh, const unsigned short* __restrict__ zb,
    unsigned short* __restrict__ hb, float fi, int N)
{
    long n = (long)blockIdx.x * 16 + (threadIdx.x >> 4);
    if (n >= N) return;
    int c = (threadIdx.x & 15) * 8;

    ushort8v zv = *reinterpret_cast<const ushort8v*>(zb + n * HID + c);
    ushort8v hv;
    if constexpr (!FIRST) hv = *reinterpret_cast<const ushort8v*>(hb + n * HID + c);
    float di = dis[n];
    float rd = di * di;                       // 1/deg
    float acc[8];
#pragma unroll
    for (int j = 0; j < 8; ++j) acc[j] = fmaxf(bf2f(zv[j]) + root[c + j], 0.f) * rd;

    int jb = ptr[n], je = ptr[n + 1];
    int j2 = jb;
    for (; j2 + 1 < je; j2 += 2) {            // paired: 2 gathers in flight
        int4 e0 = edata[j2];
        int4 e1 = edata[j2 + 1];
        ushort8v z0 = *reinterpret_cast<const ushort8v*>(zb + (long)e0.x * HID + c);
        ushort8v z1 = *reinterpret_cast<const ushort8v*>(zb + (long)e1.x * HID + c);
        const float* c0p = comb + e0.y * HID + c;
        const float* c1p = comb + e1.y * HID + c;
        floatx4 c0a = *reinterpret_cast<const floatx4*>(c0p);
        floatx4 c0b = *reinterpret_cast<const floatx4*>(c0p + 4);
        floatx4 c1a = *reinterpret_cast<const floatx4*>(c1p);
        floatx4 c1b = *reinterpret_cast<const floatx4*>(c1p + 4);
        float n0 = __builtin_bit_cast(float, e0.z);
        float n1 = __builtin_bit_cast(float, e1.z);
#pragma unroll
        for (int j = 0; j < 4; ++j) {
            acc[j]     += fmaxf(bf2f(z0[j])     + c0a[j], 0.f) * n0;
            acc[j + 4] += fmaxf(bf2f(z0[j + 4]) + c0b[j], 0.f) * n0;
            acc[j]     += fmaxf(bf2f(z1[j])     + c1a[j], 0.f) * n1;
            acc[j + 4] += fmaxf(bf2f(z1[j + 4]) + c1b[j], 0.f) * n1;
        }
    }
    if (j2 < je) {
        int4 e0 = edata[j2];
        ushort8v z0 = *reinterpret_cast<const ushort8v*>(zb + (long)e0.x * HID + c);
        const float* c0p = comb + e0.y * HID + c;
        floatx4 c0a = *reinterpret_cast<const floatx4*>(c0p);
        floatx4 c0b = *reinterpret_cast<const floatx4*>(c0p + 4);
        float n0 = __builtin_bit_cast(float, e0.z);
#pragma unroll
        for (int j = 0; j < 4; ++j) {
            acc[j]     += fmaxf(bf2f(z0[j])     + c0a[j], 0.f) * n0;
            acc[j + 4] += fmaxf(bf2f(z0[j + 4]) + c0b[j], 0.f) * n0;
        }
    }

    ushort8v o;
#pragma unroll
    for (int j = 0; j < 8; ++j) {
        float t = fmaxf(acc[j], 0.f) * bnsc[c + j] + bnsh[c + j];
        float h;
        if constexpr (FIRST) h = t;
        else h = fi * bf2f(hv[j]) + (1.f - fi) * t;
        o[j] = f2bf(h);
    }
    *reinterpret_cast<ushort8v*>(hb + n * HID + c) = o;
}

// ---------------- z = h @ W^T + b  (permuted layout: NO LDS, no barriers) ----
// C fragment IS contiguous in phys layout: for fixed (q,r), lane l15's 8
// values (nt=0..7) = logical cols {nt*16+l15} = phys {l15*8..l15*8+7} ->
// one 16B store/lane, 256B/row. Wb is K-permuted to match A. No launch
// bound (rounds 9-11 lesson: any cap spills the unified VGPR/AGPR file).
__global__ void gemm_kernel(
    const unsigned short* __restrict__ hb, const unsigned short* __restrict__ Wb,
    const float* __restrict__ bias, unsigned short* __restrict__ zb, int N)
{
    int tid = threadIdx.x;
    int wave = tid >> 6;
    int lane = tid & 63;
    int l15 = lane & 15;
    int q = lane >> 4;
    long row0 = (long)blockIdx.x * 128 + wave * 32;

    short8 a[2][4];
#pragma unroll
    for (int mt = 0; mt < 2; ++mt) {
        long rl = row0 + mt * 16 + l15;
        if (rl > (long)N - 1) rl = (long)N - 1;
        const unsigned short* ap = hb + rl * HID + q * 8;
#pragma unroll
        for (int kb = 0; kb < 4; ++kb)
            a[mt][kb] = *reinterpret_cast<const short8*>(ap + kb * 32);
    }

    floatx4 acc[2][8];
#pragma unroll
    for (int mt = 0; mt < 2; ++mt)
#pragma unroll
        for (int nt = 0; nt < 8; ++nt) {
            floatx4 zz = {0.f, 0.f, 0.f, 0.f};
            acc[mt][nt] = zz;
        }

#pragma unroll
    for (int nt = 0; nt < 8; ++nt) {
        const unsigned short* bp = Wb + (nt * 16 + l15) * HID + q * 8;
#pragma unroll
        for (int kb = 0; kb < 4; ++kb) {
            short8 b = *reinterpret_cast<const short8*>(bp + kb * 32);
            acc[0][nt] = __builtin_amdgcn_mfma_f32_16x16x32_bf16(a[0][kb], b, acc[0][nt], 0, 0, 0);
            acc[1][nt] = __builtin_amdgcn_mfma_f32_16x16x32_bf16(a[1][kb], b, acc[1][nt], 0, 0, 0);
        }
    }

    float bi[8];
#pragma unroll
    for (int nt = 0; nt < 8; ++nt) bi[nt] = bias[nt * 16 + l15];   // logical col

#pragma unroll
    for (int mt = 0; mt < 2; ++mt)
#pragma unroll
        for (int r = 0; r < 4; ++r) {
            long gr = row0 + mt * 16 + q * 4 + r;
            if (gr < N) {
                ushort8v o;
#pragma unroll
                for (int nt = 0; nt < 8; ++nt)
                    o[nt] = f2bf(acc[mt][nt][r] + bi[nt]);
                *reinterpret_cast<ushort8v*>(zb + gr * HID + l15 * 8) = o;
            }
        }
}

// ---------------- final linear via MFMA (K permuted; task dim unchanged) -----
__global__ __launch_bounds__(256) void linmm_kernel(
    const unsigned short* __restrict__ pb, const unsigned short* __restrict__ Wb,
    const float* __restrict__ bias, float* __restrict__ out, int G)
{
    int wave = threadIdx.x >> 6;
    int lane = threadIdx.x & 63;
    int l15 = lane & 15;
    int q = lane >> 4;
    long row0 = (long)blockIdx.x * 128 + wave * 32;

    short8 a[2][4];
#pragma unroll
    for (int mt = 0; mt < 2; ++mt) {
        long rl = row0 + mt * 16 + l15;
        if (rl > (long)G - 1) rl = (long)G - 1;
        const unsigned short* ap = pb + rl * HID + q * 8;
#pragma unroll
        for (int kb = 0; kb < 4; ++kb)
            a[mt][kb] = *reinterpret_cast<const short8*>(ap + kb * 32);
    }

    floatx4 acc[2][8];
#pragma unroll
    for (int mt = 0; mt < 2; ++mt)
#pragma unroll
        for (int nt = 0; nt < 8; ++nt) {
            floatx4 zz = {0.f, 0.f, 0.f, 0.f};
            acc[mt][nt] = zz;
        }

#pragma unroll
    for (int nt = 0; nt < 8; ++nt) {
        const unsigned short* bp = Wb + (nt * 16 + l15) * HID + q * 8;
#pragma unroll
        for (int kb = 0; kb < 4; ++kb) {
            short8 b = *reinterpret_cast<const short8*>(bp + kb * 32);
            acc[0][nt] = __builtin_amdgcn_mfma_f32_16x16x32_bf16(a[0][kb], b, acc[0][nt], 0, 0, 0);
            acc[1][nt] = __builtin_amdgcn_mfma_f32_16x16x32_bf16(a[1][kb], b, acc[1][nt], 0, 0, 0);
        }
    }

    float bi[8];
#pragma unroll
    for (int nt = 0; nt < 8; ++nt) bi[nt] = bias[nt * 16 + l15];

#pragma unroll
    for (int mt = 0; mt < 2; ++mt)
#pragma unroll
        for (int r = 0; r < 4; ++r) {
            long rr = row0 + mt * 16 + q * 4 + r;
            if (rr < G) {
                float* op = out + rr * HID + l15;
#pragma unroll
                for (int nt = 0; nt < 8; ++nt)
                    op[nt * 16] = acc[mt][nt][r] + bi[nt];
            }
        }
}

// ---------------- mean-pool: one WAVE per graph (no LDS, no barriers) --------
__global__ __launch_bounds__(256) void pool_kernel(
    const unsigned short* __restrict__ hb, const int* __restrict__ gptr,
    unsigned short* __restrict__ pb, int G)
{
    int g = blockIdx.x * 4 + (threadIdx.x >> 6);
    if (g >= G) return;
    int lane = threadIdx.x & 63;
    int c = lane * 2;
    int lo = gptr[g], hi = gptr[g + 1];

    float a0 = 0.f, a1 = 0.f, b0 = 0.f, b1 = 0.f;
    int n = lo;
    for (; n + 1 < hi; n += 2) {
        unsigned v0 = *reinterpret_cast<const unsigned*>(hb + (long)n * HID + c);
        unsigned v1 = *reinterpret_cast<const unsigned*>(hb + (long)(n + 1) * HID + c);
        a0 += bf2f((unsigned short)(v0 & 0xFFFF));
        a1 += bf2f((unsigned short)(v0 >> 16));
        b0 += bf2f((unsigned short)(v1 & 0xFFFF));
        b1 += bf2f((unsigned short)(v1 >> 16));
    }
    if (n < hi) {
        unsigned v0 = *reinterpret_cast<const unsigned*>(hb + (long)n * HID + c);
        a0 += bf2f((unsigned short)(v0 & 0xFFFF));
        a1 += bf2f((unsigned short)(v0 >> 16));
    }
    float cnt = (hi > lo) ? (float)(hi - lo) : 1.f;
    float s0 = (a0 + b0) / cnt;
    float s1 = (a1 + b1) / cnt;
    unsigned o = (unsigned)f2bf(s0) | ((unsigned)f2bf(s1) << 16);
    *reinterpret_cast<unsigned*>(pb + (long)g * HID + c) = o;
}

extern "C" void kernel_launch(void* const* d_in, const int* in_sizes, int n_in,
                              void* d_out, int out_size, void* d_ws, size_t ws_size,
                              hipStream_t stream)
{
    const int* x          = (const int*)d_in[0];
    const int* ei         = (const int*)d_in[1];
    const int* attr       = (const int*)d_in[2];
    const int* batch      = (const int*)d_in[3];
    const float* atom_emb = (const float*)d_in[4];
    const float* bond_emb = (const float*)d_in[5];
    const float* conv_W   = (const float*)d_in[6];
    const float* conv_b   = (const float*)d_in[7];
    const float* root     = (const float*)d_in[8];
    const float* gamma    = (const float*)d_in[9];
    const float* beta     = (const float*)d_in[10];
    const float* mean     = (const float*)d_in[11];
    const float* var      = (const float*)d_in[12];
    const float* lin_W    = (const float*)d_in[13];
    const float* lin_b    = (const float*)d_in[14];
    float* out = (float*)d_out;

    const int N = in_sizes[0] / 9;
    const int E = in_sizes[1] / 2;
    const int G = out_size / HID;
    const int B = (N + 255) / 256;

    auto al = [](size_t b) { return (b + 255) & ~(size_t)255; };
    const size_t need =
        al((size_t)N * HID * 2) +         // hb
        al((size_t)N * HID * 2) +         // zb
        al((size_t)(N + 1) * 4) +         // ptr
        al((size_t)E * 16) +              // edata (int4)
        al((size_t)N * 4) +               // indeg (= cursor)
        al((size_t)2048 * 4) * 2 +        // partial + offs
        al((size_t)(G + 1) * 4) +         // gptr
        al((size_t)(G + 128) * HID * 2) + // pooled bf16 (dis aliases; +tail pad)
        al((size_t)60 * HID * 4) +        // comb (fp32, permuted)
        al((size_t)HID * 4) * 4 +         // bnsc + bnsh + rootp + cbp
        al((size_t)HID * HID * 2) * 2 +   // Wb + linWb (K permuted)
        al((size_t)AROWS * HID * 2);      // EWb (permuted)

    if (ws_size < need || B > 2048) {
        float v = (B > 2048) ? 3000.f : (1000.f + (float)(ws_size >> 20));
        long n = (long)out_size;
        diag_kernel<<<(int)((n + 255) / 256), 256, 0, stream>>>(out, n, v);
        return;
    }

    char* wsp = (char*)d_ws;
    size_t used = 0;
    auto alloc = [&](size_t bytes) { char* p = wsp + used; used += al(bytes); return p; };
    unsigned short* hb = (unsigned short*)alloc((size_t)N * HID * 2);
    unsigned short* zb = (unsigned short*)alloc((size_t)N * HID * 2);
    int* ptr      = (int*)alloc((size_t)(N + 1) * 4);
    int4* edata   = (int4*)alloc((size_t)E * 16);
    int* indeg    = (int*)alloc((size_t)N * 4);
    int* cursor   = indeg;                    // in-place scan (element-wise safe)
    int* partial  = (int*)alloc((size_t)2048 * 4);
    int* offs     = (int*)alloc((size_t)2048 * 4);
    int* gptr     = (int*)alloc((size_t)(G + 1) * 4);
    unsigned short* pb = (unsigned short*)alloc((size_t)(G + 128) * HID * 2);
    float* dis    = (float*)pb;               // alias: dis dead before pool writes pb
    float* comb   = (float*)alloc((size_t)60 * HID * 4);
    float* bnsc   = (float*)alloc((size_t)HID * 4);
    float* bnsh   = (float*)alloc((size_t)HID * 4);
    float* rootp  = (float*)alloc((size_t)HID * 4);
    float* cbp    = (float*)alloc((size_t)HID * 4);
    unsigned short* Wb    = (unsigned short*)alloc((size_t)HID * HID * 2);
    unsigned short* linWb = (unsigned short*)alloc((size_t)HID * HID * 2);
    unsigned short* EWb   = (unsigned short*)alloc((size_t)AROWS * HID * 2);

    // ---- prologue (6 launches) ----
    init_kernel<<<B + 159 + 87, 256, 0, stream>>>(dis, indeg, B, N,
            conv_W, Wb, lin_W, linWb, bond_emb, comb,
            gamma, beta, mean, var, bnsc, bnsh,
            root, conv_b, rootp, cbp, atom_emb, EWb);
    hist_kernel<<<1024, 256, 0, stream>>>(ei, dis, indeg, E);
    bsum_kernel<<<B, 256, 0, stream>>>(indeg, partial, dis, N);
    scan1_kernel<<<1, 256, 0, stream>>>(partial, offs, ptr, B, N);
    scan2_kernel<<<B, 256, 0, stream>>>(indeg, offs, ptr, cursor, N);
    fillcsr_kernel<<<1024, 256, 0, stream>>>(ei, attr, dis, cursor, edata,
                                             batch, gptr, E, N, G);

    // ---- loop (i=1 is identity, skipped; fis = {0,2,3,4}) ----
    const int gemm_blocks = (N + 127) / 128;
    const int node_blocks = (N + 15) / 16;
    enc_kernel<<<node_blocks, 256, 0, stream>>>(x, EWb, cbp, zb, N);
    agg_kernel<true ><<<node_blocks, 256, 0, stream>>>(ptr, edata, comb, dis,
            rootp, bnsc, bnsh, zb, hb, 0.f, N);
    const float fis[3] = {2.f, 3.f, 4.f};
    for (int t = 0; t < 3; ++t) {
        gemm_kernel<<<gemm_blocks, 256, 0, stream>>>(hb, Wb, conv_b, zb, N);
        agg_kernel<false><<<node_blocks, 256, 0, stream>>>(ptr, edata, comb, dis,
                rootp, bnsc, bnsh, zb, hb, fis[t], N);
    }

    // ---- mean-pool (wave/graph) + MFMA final linear (fp32 out) ----
    pool_kernel<<<(G + 3) / 4, 256, 0, stream>>>(hb, gptr, pb, G);
    linmm_kernel<<<(G + 127) / 128, 256, 0, stream>>>(pb, linWb, lin_b, out, G);
}

// Round 14
// 648.037 us; speedup vs baseline: 1.0177x; 1.0177x over previous
//
#include <hip/hip_runtime.h>

#define HID 128
#define AROWS 173   // sum(ATOM_DIMS) = 173 (offsets end at 171, last dim = 2)

// Global feature-dim permutation: phys position p holds logical column
// c(p) = (p&7)*16 + (p>>3).  Inverse: p(c) = (c&15)*8 + (c>>4).
// Makes the MFMA C-fragment contiguous in phys layout -> gemm needs no LDS.
__device__ __forceinline__ int lcol(int p) { return ((p & 7) << 4) | (p >> 3); }

typedef __attribute__((ext_vector_type(8))) short short8;
typedef __attribute__((ext_vector_type(8))) unsigned short ushort8v;
typedef __attribute__((ext_vector_type(4))) float floatx4;
typedef __attribute__((ext_vector_type(4))) unsigned short ushort4v;

__device__ __forceinline__ unsigned short f2bf(float f) {
    unsigned u = __builtin_bit_cast(unsigned, f);
    u += 0x7FFF + ((u >> 16) & 1);           // RNE
    return (unsigned short)(u >> 16);
}
__device__ __forceinline__ float bf2f(unsigned short s) {
    unsigned u = ((unsigned)s) << 16;
    return __builtin_bit_cast(float, u);
}

// ---------------- diagnostic ----------------
__global__ void diag_kernel(float* __restrict__ out, long n, float val)
{
    long i = (long)blockIdx.x * blockDim.x + threadIdx.x;
    if (i < n) out[i] = val;
}

// ---------------- merged init: fillrd | tables (permuted, bf16 comb) | EW ----
// blocks [0,NB): zero dis+indeg | [NB,NB+64): conv_W cvt | +64..128: lin_W cvt
// | +128..158: comb bf16 | +158: BN/root/cb | +159..246: EW rows (2/block)
__global__ __launch_bounds__(256) void init_kernel(
    float* __restrict__ dis, int* __restrict__ indeg, int NB, int N,
    const float* __restrict__ conv_W, unsigned short* __restrict__ Wb,
    const float* __restrict__ lin_W, unsigned short* __restrict__ linWb,
    const float* __restrict__ bond_emb, unsigned short* __restrict__ comb,
    const float* __restrict__ gamma, const float* __restrict__ beta,
    const float* __restrict__ mean, const float* __restrict__ var,
    float* __restrict__ bnsc, float* __restrict__ bnsh,
    const float* __restrict__ root, const float* __restrict__ conv_b,
    float* __restrict__ rootp, float* __restrict__ cbp,
    const float* __restrict__ atom_emb, unsigned short* __restrict__ EWb)
{
    int blk = blockIdx.x;
    int tid = threadIdx.x;
    if (blk < NB) {
        int i = blk * 256 + tid;
        if (i < N) { dis[i] = 0.f; indeg[i] = 0; }
        return;
    }
    blk -= NB;
    if (blk < 64) {
        int i = blk * 256 + tid;
        int row = i >> 7, p = i & 127;
        Wb[i] = f2bf(conv_W[row * HID + lcol(p)]);
    } else if (blk < 128) {
        int i = (blk - 64) * 256 + tid;
        int row = i >> 7, p = i & 127;
        linWb[i] = f2bf(lin_W[row * HID + lcol(p)]);
    } else if (blk < 158) {
        int i = (blk - 128) * 2 + (tid >> 7);     // combo row
        int p = tid & 127;
        int c = lcol(p);
        int a0 = i / 12, a1 = (i % 12) / 2, a2 = i % 2;
        comb[i * HID + p] = f2bf(bond_emb[a0 * HID + c] + bond_emb[(5 + a1) * HID + c]
                               + bond_emb[(11 + a2) * HID + c]);
    } else if (blk == 158) {
        if (tid < HID) {
            int c = lcol(tid);
            float sc = gamma[c] * rsqrtf(var[c] + 1e-5f);
            bnsc[tid] = sc;
            bnsh[tid] = beta[c] - mean[c] * sc;
            rootp[tid] = root[c];
            cbp[tid] = conv_b[c];
        }
    } else {
        // EW = atom_emb @ conv_W^T, 2 rows/block, stored permuted
        int r = (blk - 159) * 2 + (tid >> 7);
        if (r >= AROWS) return;
        int c = tid & 127;                        // logical col
        const float* er = atom_emb + (long)r * HID;
        const float* wr = conv_W + (long)c * HID;
        float acc = 0.f;
#pragma unroll 4
        for (int k = 0; k < HID; k += 4) {
            floatx4 e4 = *reinterpret_cast<const floatx4*>(er + k);
            floatx4 w4 = *reinterpret_cast<const floatx4*>(wr + k);
            acc += e4[0] * w4[0] + e4[1] * w4[1] + e4[2] * w4[2] + e4[3] * w4[3];
        }
        EWb[(long)r * HID + ((c & 15) * 8 + (c >> 4))] = f2bf(acc);
    }
}

// ---------------- merged: out-degree (row, into dis) + in-degree (col) -------
__global__ void hist_kernel(const int* __restrict__ ei, float* __restrict__ dis,
                            int* __restrict__ indeg, int E)
{
    for (int e = blockIdx.x * blockDim.x + threadIdx.x; e < E; e += gridDim.x * blockDim.x) {
        atomicAdd(&dis[ei[e]], 1.f);
        atomicAdd(&indeg[ei[E + e]], 1);
    }
}

// ---------------- CSR scan chain (node order) + fdeg fold --------------------
__global__ __launch_bounds__(256) void bsum_kernel(
    const int* __restrict__ indeg, int* __restrict__ partial,
    float* __restrict__ dis, int N)
{
    __shared__ int s[256];
    int tid = threadIdx.x;
    int i = blockIdx.x * 256 + tid;
    int v = (i < N) ? indeg[i] : 0;
    s[tid] = v;
    if (i < N) dis[i] = rsqrtf(dis[i] + 1.f);     // fdeg folded (hist complete)
    __syncthreads();
    for (int d = 128; d > 0; d >>= 1) {
        if (tid < d) s[tid] += s[tid + d];
        __syncthreads();
    }
    if (tid == 0) partial[blockIdx.x] = s[0];
}

__global__ __launch_bounds__(256) void scan1_kernel(
    const int* __restrict__ partial, int* __restrict__ offs,
    int* __restrict__ ptr, int B, int N)
{
    __shared__ int s[256];
    __shared__ int carry_s;
    int tid = threadIdx.x;
    if (tid == 0) carry_s = 0;
    __syncthreads();
    for (int base = 0; base < B; base += 256) {
        int i = base + tid;
        int v = (i < B) ? partial[i] : 0;
        s[tid] = v;
        __syncthreads();
        for (int d = 1; d < 256; d <<= 1) {
            int t = (tid >= d) ? s[tid - d] : 0;
            __syncthreads();
            s[tid] += t;
            __syncthreads();
        }
        int carry = carry_s;
        if (i < B) offs[i] = carry + s[tid] - v;
        __syncthreads();
        if (tid == 0) carry_s = carry + s[255];
        __syncthreads();
    }
    if (tid == 0) ptr[N] = carry_s;
}

// in-place safe: cursor may alias indeg (read-before-write per element)
__global__ __launch_bounds__(256) void scan2_kernel(
    const int* __restrict__ indeg, const int* __restrict__ offs,
    int* __restrict__ ptr, int* __restrict__ cursor, int N)
{
    __shared__ int s[256];
    int tid = threadIdx.x;
    int i = blockIdx.x * 256 + tid;
    int v = (i < N) ? indeg[i] : 0;
    s[tid] = v;
    __syncthreads();
    for (int d = 1; d < 256; d <<= 1) {
        int t = (tid >= d) ? s[tid - d] : 0;
        __syncthreads();
        s[tid] += t;
        __syncthreads();
    }
    if (i < N) {
        int ex = offs[blockIdx.x] + s[tid] - v;
        ptr[i] = ex;
        cursor[i] = ex;
    }
}

// ---------------- CSR fill {row, ci|bf16(norm)<<16} + (folded) gptr ----------
__global__ void fillcsr_kernel(const int* __restrict__ ei, const int* __restrict__ attr,
                               const float* __restrict__ dis, int* __restrict__ cursor,
                               int2* __restrict__ edata, const int* __restrict__ batch,
                               int* __restrict__ gptr, int E, int N, int G)
{
    for (int e = blockIdx.x * blockDim.x + threadIdx.x; e < E; e += gridDim.x * blockDim.x) {
        int r   = ei[e];
        int col = ei[E + e];
        int pos = atomicAdd(&cursor[col], 1);
        int ci  = attr[e * 3] * 12 + attr[e * 3 + 1] * 2 + attr[e * 3 + 2];
        float nrm = dis[r] * dis[col];
        int2 ed;
        ed.x = r;
        ed.y = ci | ((int)f2bf(nrm) << 16);
        edata[pos] = ed;
    }
    for (int n = blockIdx.x * blockDim.x + threadIdx.x; n < N; n += gridDim.x * blockDim.x) {
        int b = batch[n];
        int bp = (n == 0) ? -1 : batch[n - 1];
        for (int g = bp + 1; g <= b; ++g) gptr[g] = n;
        if (n == N - 1)
            for (int g = b + 1; g <= G; ++g) gptr[g] = N;
    }
}

// ---------------- encode: z = sum_f EW[idx_f] + b (permuted layout) ----------
__global__ __launch_bounds__(256) void enc_kernel(
    const int* __restrict__ x, const unsigned short* __restrict__ EWb,
    const float* __restrict__ cbp, unsigned short* __restrict__ zb, int N)
{
    long n = (long)blockIdx.x * 16 + (threadIdx.x >> 4);
    if (n >= N) return;
    int c = (threadIdx.x & 15) * 8;
    const int OFF[9] = {0, 119, 123, 135, 147, 157, 163, 169, 171};

    float acc[8];
#pragma unroll
    for (int j = 0; j < 8; ++j) acc[j] = cbp[c + j];

#pragma unroll
    for (int f = 0; f < 9; ++f) {
        int idx = x[n * 9 + f] + OFF[f];              // 16-lane broadcast load
        ushort8v v = *reinterpret_cast<const ushort8v*>(EWb + (long)idx * HID + c);
#pragma unroll
        for (int j = 0; j < 8; ++j) acc[j] += bf2f(v[j]);
    }

    ushort8v o;
#pragma unroll
    for (int j = 0; j < 8; ++j) o[j] = f2bf(acc[j]);
    *reinterpret_cast<ushort8v*>(zb + n * HID + c) = o;
}

// ---------------- agg: one node per 16-lane group (permuted layout) ----------
// Round-12 configuration (bf16 comb + packed int2 edata) — best measured.
template<bool FIRST>
__global__ __launch_bounds__(256) void agg_kernel(
    const int* __restrict__ ptr, const int2* __restrict__ edata,
    const unsigned short* __restrict__ comb, const float* __restrict__ dis,
    const float* __restrict__ root, const float* __restrict__ bnsc,
    const float* __restrict__ bnsh, const unsigned short* __restrict__ zb,
    unsigned short* __restrict__ hb, float fi, int N)
{
    long n = (long)blockIdx.x * 16 + (threadIdx.x >> 4);
    if (n >= N) return;
    int c = (threadIdx.x & 15) * 8;

    ushort8v zv = *reinterpret_cast<const ushort8v*>(zb + n * HID + c);
    ushort8v hv;
    if constexpr (!FIRST) hv = *reinterpret_cast<const ushort8v*>(hb + n * HID + c);
    float di = dis[n];
    float rd = di * di;                       // 1/deg
    float acc[8];
#pragma unroll
    for (int j = 0; j < 8; ++j) acc[j] = fmaxf(bf2f(zv[j]) + root[c + j], 0.f) * rd;

    int jb = ptr[n], je = ptr[n + 1];
    int j2 = jb;
    for (; j2 + 1 < je; j2 += 2) {            // paired: 2 gathers in flight
        int2 e0 = edata[j2];
        int2 e1 = edata[j2 + 1];
        ushort8v z0 = *reinterpret_cast<const ushort8v*>(zb + (long)e0.x * HID + c);
        ushort8v z1 = *reinterpret_cast<const ushort8v*>(zb + (long)e1.x * HID + c);
        ushort8v c0 = *reinterpret_cast<const ushort8v*>(comb + (e0.y & 0xFF) * HID + c);
        ushort8v c1 = *reinterpret_cast<const ushort8v*>(comb + (e1.y & 0xFF) * HID + c);
        float n0 = bf2f((unsigned short)(((unsigned)e0.y) >> 16));
        float n1 = bf2f((unsigned short)(((unsigned)e1.y) >> 16));
#pragma unroll
        for (int j = 0; j < 8; ++j) {
            acc[j] += fmaxf(bf2f(z0[j]) + bf2f(c0[j]), 0.f) * n0;
            acc[j] += fmaxf(bf2f(z1[j]) + bf2f(c1[j]), 0.f) * n1;
        }
    }
    if (j2 < je) {
        int2 e0 = edata[j2];
        ushort8v z0 = *reinterpret_cast<const ushort8v*>(zb + (long)e0.x * HID + c);
        ushort8v c0 = *reinterpret_cast<const ushort8v*>(comb + (e0.y & 0xFF) * HID + c);
        float n0 = bf2f((unsigned short)(((unsigned)e0.y) >> 16));
#pragma unroll
        for (int j = 0; j < 8; ++j)
            acc[j] += fmaxf(bf2f(z0[j]) + bf2f(c0[j]), 0.f) * n0;
    }

    ushort8v o;
#pragma unroll
    for (int j = 0; j < 8; ++j) {
        float t = fmaxf(acc[j], 0.f) * bnsc[c + j] + bnsh[c + j];
        float h;
        if constexpr (FIRST) h = t;
        else h = fi * bf2f(hv[j]) + (1.f - fi) * t;
        o[j] = f2bf(h);
    }
    *reinterpret_cast<ushort8v*>(hb + n * HID + c) = o;
}

// ---------------- z = h @ W^T + b  (permuted layout: NO LDS, no barriers) ----
// C fragment IS contiguous in phys layout: for fixed (q,r), lane l15's 8
// values (nt=0..7) = logical cols {nt*16+l15} = phys {l15*8..l15*8+7} ->
// one 16B store/lane, 256B/row. Wb is K-permuted to match A. No launch
// bound (rounds 9-11 lesson: any cap spills the unified VGPR/AGPR file).
__global__ void gemm_kernel(
    const unsigned short* __restrict__ hb, const unsigned short* __restrict__ Wb,
    const float* __restrict__ bias, unsigned short* __restrict__ zb, int N)
{
    int tid = threadIdx.x;
    int wave = tid >> 6;
    int lane = tid & 63;
    int l15 = lane & 15;
    int q = lane >> 4;
    long row0 = (long)blockIdx.x * 128 + wave * 32;

    short8 a[2][4];
#pragma unroll
    for (int mt = 0; mt < 2; ++mt) {
        long rl = row0 + mt * 16 + l15;
        if (rl > (long)N - 1) rl = (long)N - 1;
        const unsigned short* ap = hb + rl * HID + q * 8;
#pragma unroll
        for (int kb = 0; kb < 4; ++kb)
            a[mt][kb] = *reinterpret_cast<const short8*>(ap + kb * 32);
    }

    floatx4 acc[2][8];
#pragma unroll
    for (int mt = 0; mt < 2; ++mt)
#pragma unroll
        for (int nt = 0; nt < 8; ++nt) {
            floatx4 zz = {0.f, 0.f, 0.f, 0.f};
            acc[mt][nt] = zz;
        }

#pragma unroll
    for (int nt = 0; nt < 8; ++nt) {
        const unsigned short* bp = Wb + (nt * 16 + l15) * HID + q * 8;
#pragma unroll
        for (int kb = 0; kb < 4; ++kb) {
            short8 b = *reinterpret_cast<const short8*>(bp + kb * 32);
            acc[0][nt] = __builtin_amdgcn_mfma_f32_16x16x32_bf16(a[0][kb], b, acc[0][nt], 0, 0, 0);
            acc[1][nt] = __builtin_amdgcn_mfma_f32_16x16x32_bf16(a[1][kb], b, acc[1][nt], 0, 0, 0);
        }
    }

    float bi[8];
#pragma unroll
    for (int nt = 0; nt < 8; ++nt) bi[nt] = bias[nt * 16 + l15];   // logical col

#pragma unroll
    for (int mt = 0; mt < 2; ++mt)
#pragma unroll
        for (int r = 0; r < 4; ++r) {
            long gr = row0 + mt * 16 + q * 4 + r;
            if (gr < N) {
                ushort8v o;
#pragma unroll
                for (int nt = 0; nt < 8; ++nt)
                    o[nt] = f2bf(acc[mt][nt][r] + bi[nt]);
                *reinterpret_cast<ushort8v*>(zb + gr * HID + l15 * 8) = o;
            }
        }
}

// ---------------- final linear via MFMA (K permuted; task dim unchanged) -----
__global__ __launch_bounds__(256) void linmm_kernel(
    const unsigned short* __restrict__ pb, const unsigned short* __restrict__ Wb,
    const float* __restrict__ bias, float* __restrict__ out, int G)
{
    int wave = threadIdx.x >> 6;
    int lane = threadIdx.x & 63;
    int l15 = lane & 15;
    int q = lane >> 4;
    long row0 = (long)blockIdx.x * 128 + wave * 32;

    short8 a[2][4];
#pragma unroll
    for (int mt = 0; mt < 2; ++mt) {
        long rl = row0 + mt * 16 + l15;
        if (rl > (long)G - 1) rl = (long)G - 1;
        const unsigned short* ap = pb + rl * HID + q * 8;
#pragma unroll
        for (int kb = 0; kb < 4; ++kb)
            a[mt][kb] = *reinterpret_cast<const short8*>(ap + kb * 32);
    }

    floatx4 acc[2][8];
#pragma unroll
    for (int mt = 0; mt < 2; ++mt)
#pragma unroll
        for (int nt = 0; nt < 8; ++nt) {
            floatx4 zz = {0.f, 0.f, 0.f, 0.f};
            acc[mt][nt] = zz;
        }

#pragma unroll
    for (int nt = 0; nt < 8; ++nt) {
        const unsigned short* bp = Wb + (nt * 16 + l15) * HID + q * 8;
#pragma unroll
        for (int kb = 0; kb < 4; ++kb) {
            short8 b = *reinterpret_cast<const short8*>(bp + kb * 32);
            acc[0][nt] = __builtin_amdgcn_mfma_f32_16x16x32_bf16(a[0][kb], b, acc[0][nt], 0, 0, 0);
            acc[1][nt] = __builtin_amdgcn_mfma_f32_16x16x32_bf16(a[1][kb], b, acc[1][nt], 0, 0, 0);
        }
    }

    float bi[8];
#pragma unroll
    for (int nt = 0; nt < 8; ++nt) bi[nt] = bias[nt * 16 + l15];

#pragma unroll
    for (int mt = 0; mt < 2; ++mt)
#pragma unroll
        for (int r = 0; r < 4; ++r) {
            long rr = row0 + mt * 16 + q * 4 + r;
            if (rr < G) {
                float* op = out + rr * HID + l15;
#pragma unroll
                for (int nt = 0; nt < 8; ++nt)
                    op[nt * 16] = acc[mt][nt][r] + bi[nt];
            }
        }
}

// ---------------- mean-pool: one WAVE per graph (no LDS, no barriers) --------
__global__ __launch_bounds__(256) void pool_kernel(
    const unsigned short* __restrict__ hb, const int* __restrict__ gptr,
    unsigned short* __restrict__ pb, int G)
{
    int g = blockIdx.x * 4 + (threadIdx.x >> 6);
    if (g >= G) return;
    int lane = threadIdx.x & 63;
    int c = lane * 2;
    int lo = gptr[g], hi = gptr[g + 1];

    float a0 = 0.f, a1 = 0.f, b0 = 0.f, b1 = 0.f;
    int n = lo;
    for (; n + 1 < hi; n += 2) {
        unsigned v0 = *reinterpret_cast<const unsigned*>(hb + (long)n * HID + c);
        unsigned v1 = *reinterpret_cast<const unsigned*>(hb + (long)(n + 1) * HID + c);
        a0 += bf2f((unsigned short)(v0 & 0xFFFF));
        a1 += bf2f((unsigned short)(v0 >> 16));
        b0 += bf2f((unsigned short)(v1 & 0xFFFF));
        b1 += bf2f((unsigned short)(v1 >> 16));
    }
    if (n < hi) {
        unsigned v0 = *reinterpret_cast<const unsigned*>(hb + (long)n * HID + c);
        a0 += bf2f((unsigned short)(v0 & 0xFFFF));
        a1 += bf2f((unsigned short)(v0 >> 16));
    }
    float cnt = (hi > lo) ? (float)(hi - lo) : 1.f;
    float s0 = (a0 + b0) / cnt;
    float s1 = (a1 + b1) / cnt;
    unsigned o = (unsigned)f2bf(s0) | ((unsigned)f2bf(s1) << 16);
    *reinterpret_cast<unsigned*>(pb + (long)g * HID + c) = o;
}

extern "C" void kernel_launch(void* const* d_in, const int* in_sizes, int n_in,
                              void* d_out, int out_size, void* d_ws, size_t ws_size,
                              hipStream_t stream)
{
    const int* x          = (const int*)d_in[0];
    const int* ei         = (const int*)d_in[1];
    const int* attr       = (const int*)d_in[2];
    const int* batch      = (const int*)d_in[3];
    const float* atom_emb = (const float*)d_in[4];
    const float* bond_emb = (const float*)d_in[5];
    const float* conv_W   = (const float*)d_in[6];
    const float* conv_b   = (const float*)d_in[7];
    const float* root     = (const float*)d_in[8];
    const float* gamma    = (const float*)d_in[9];
    const float* beta     = (const float*)d_in[10];
    const float* mean     = (const float*)d_in[11];
    const float* var      = (const float*)d_in[12];
    const float* lin_W    = (const float*)d_in[13];
    const float* lin_b    = (const float*)d_in[14];
    float* out = (float*)d_out;

    const int N = in_sizes[0] / 9;
    const int E = in_sizes[1] / 2;
    const int G = out_size / HID;
    const int B = (N + 255) / 256;

    auto al = [](size_t b) { return (b + 255) & ~(size_t)255; };
    const size_t need =
        al((size_t)N * HID * 2) +         // hb
        al((size_t)N * HID * 2) +         // zb
        al((size_t)(N + 1) * 4) +         // ptr
        al((size_t)E * 8) +               // edata (int2)
        al((size_t)N * 4) +               // indeg (= cursor)
        al((size_t)2048 * 4) * 2 +        // partial + offs
        al((size_t)(G + 1) * 4) +         // gptr
        al((size_t)(G + 128) * HID * 2) + // pooled bf16 (dis aliases; +tail pad)
        al((size_t)60 * HID * 2) +        // comb (bf16, permuted)
        al((size_t)HID * 4) * 4 +         // bnsc + bnsh + rootp + cbp
        al((size_t)HID * HID * 2) * 2 +   // Wb + linWb (K permuted)
        al((size_t)AROWS * HID * 2);      // EWb (permuted)

    if (ws_size < need || B > 2048) {
        float v = (B > 2048) ? 3000.f : (1000.f + (float)(ws_size >> 20));
        long n = (long)out_size;
        diag_kernel<<<(int)((n + 255) / 256), 256, 0, stream>>>(out, n, v);
        return;
    }

    char* wsp = (char*)d_ws;
    size_t used = 0;
    auto alloc = [&](size_t bytes) { char* p = wsp + used; used += al(bytes); return p; };
    unsigned short* hb = (unsigned short*)alloc((size_t)N * HID * 2);
    unsigned short* zb = (unsigned short*)alloc((size_t)N * HID * 2);
    int* ptr      = (int*)alloc((size_t)(N + 1) * 4);
    int2* edata   = (int2*)alloc((size_t)E * 8);
    int* indeg    = (int*)alloc((size_t)N * 4);
    int* cursor   = indeg;                    // in-place scan (element-wise safe)
    int* partial  = (int*)alloc((size_t)2048 * 4);
    int* offs     = (int*)alloc((size_t)2048 * 4);
    int* gptr     = (int*)alloc((size_t)(G + 1) * 4);
    unsigned short* pb = (unsigned short*)alloc((size_t)(G + 128) * HID * 2);
    float* dis    = (float*)pb;               // alias: dis dead before pool writes pb
    unsigned short* comb = (unsigned short*)alloc((size_t)60 * HID * 2);
    float* bnsc   = (float*)alloc((size_t)HID * 4);
    float* bnsh   = (float*)alloc((size_t)HID * 4);
    float* rootp  = (float*)alloc((size_t)HID * 4);
    float* cbp    = (float*)alloc((size_t)HID * 4);
    unsigned short* Wb    = (unsigned short*)alloc((size_t)HID * HID * 2);
    unsigned short* linWb = (unsigned short*)alloc((size_t)HID * HID * 2);
    unsigned short* EWb   = (unsigned short*)alloc((size_t)AROWS * HID * 2);

    // ---- prologue (6 launches) ----
    init_kernel<<<B + 246, 256, 0, stream>>>(dis, indeg, B, N,
            conv_W, Wb, lin_W, linWb, bond_emb, comb,
            gamma, beta, mean, var, bnsc, bnsh,
            root, conv_b, rootp, cbp, atom_emb, EWb);
    hist_kernel<<<1024, 256, 0, stream>>>(ei, dis, indeg, E);
    bsum_kernel<<<B, 256, 0, stream>>>(indeg, partial, dis, N);
    scan1_kernel<<<1, 256, 0, stream>>>(partial, offs, ptr, B, N);
    scan2_kernel<<<B, 256, 0, stream>>>(indeg, offs, ptr, cursor, N);
    fillcsr_kernel<<<1024, 256, 0, stream>>>(ei, attr, dis, cursor, edata,
                                             batch, gptr, E, N, G);

    // ---- loop (i=1 is identity, skipped; fis = {0,2,3,4}) ----
    const int gemm_blocks = (N + 127) / 128;
    const int node_blocks = (N + 15) / 16;
    enc_kernel<<<node_blocks, 256, 0, stream>>>(x, EWb, cbp, zb, N);
    agg_kernel<true ><<<node_blocks, 256, 0, stream>>>(ptr, edata, comb, dis,
            rootp, bnsc, bnsh, zb, hb, 0.f, N);
    const float fis[3] = {2.f, 3.f, 4.f};
    for (int t = 0; t < 3; ++t) {
        gemm_kernel<<<gemm_blocks, 256, 0, stream>>>(hb, Wb, conv_b, zb, N);
        agg_kernel<false><<<node_blocks, 256, 0, stream>>>(ptr, edata, comb, dis,
                rootp, bnsc, bnsh, zb, hb, fis[t], N);
    }

    // ---- mean-pool (wave/graph) + MFMA final linear (fp32 out) ----
    pool_kernel<<<(G + 3) / 4, 256, 0, stream>>>(hb, gptr, pb, G);
    linmm_kernel<<<(G + 127) / 128, 256, 0, stream>>>(pb, linWb, lin_b, out, G);
}